// Round 7
// baseline (718.552 us; speedup 1.0000x reference)
//
#include <hip/hip_runtime.h>
#include <hip/hip_bf16.h>

#define A_N 152
#define V_N 26
#define M_N 3952          // A_N*V_N, = 247*16 exactly
#define M_PAD 3968        // 62*64
#define CIN 512
#define FDIM 256
#define HW_SZ 16384
#define P_TOT 131072.0f   // 8*16384
#define TEMP_INV 14.285714285714286f
#define NGRP 2048         // 8 images * 256 groups of 64 px
#define LCAP 64           // max samples per pixel-group

typedef __attribute__((ext_vector_type(8))) short bf16x8;
typedef __attribute__((ext_vector_type(4))) float f32x4;

static __device__ __forceinline__ short f2bf(float x){
  union { float f; unsigned u; } v; v.f = x;
  unsigned r = (v.u + 0x7FFFu + ((v.u >> 16) & 1u)) >> 16;
  return (short)r;
}

// Load an MFMA 16x16x32 A/B fragment from a row-major [rows][ld] bf16 matrix.
static __device__ __forceinline__ bf16x8 ldfrag(const short* __restrict__ base, int ld,
                                                int row, int k, int lane){
  return *(const bf16x8*)(base + (size_t)(row + (lane & 15)) * ld + k + ((lane >> 4) << 3));
}

// convert+store 4 px of channel tid into the XOR-swizzled [px][c] LDS tile.
// float4 BY VALUE (R1 lesson: address-taken float4 arrays go to scratch).
static __device__ __forceinline__ void cvt4(short* __restrict__ lds, float4 v,
                                            int px, int tid){
  lds[(px+0)*512 + (tid ^ (((px+0)&7)<<3))] = f2bf(v.x);
  lds[(px+1)*512 + (tid ^ (((px+1)&7)<<3))] = f2bf(v.y);
  lds[(px+2)*512 + (tid ^ (((px+2)&7)<<3))] = f2bf(v.z);
  lds[(px+3)*512 + (tid ^ (((px+3)&7)<<3))] = f2bf(v.w);
}

// ---------------------------------------------------------------- weights cast (all 4 at once)
__global__ void castw_kernel(const float* __restrict__ a0, short* __restrict__ o0,
                             const float* __restrict__ a1, short* __restrict__ o1,
                             const float* __restrict__ a2, short* __restrict__ o2,
                             const float* __restrict__ a3, short* __restrict__ o3){
  const float* a; short* o; int n;
  switch (blockIdx.y){
    case 0: a = a0; o = o0; n = CIN*CIN; break;
    case 1: a = a1; o = o1; n = CIN*CIN; break;
    case 2: a = a2; o = o2; n = FDIM*CIN; break;
    default: a = a3; o = o3; n = FDIM*CIN; break;
  }
  int i = blockIdx.x * 256 + threadIdx.x;
  if (i < n) o[i] = f2bf(a[i]);
}

// ---------------------------------------------------------------- sample -> pixel-group lists
// Entry packs (px<<16)|m so the stats gather needs no dependent si load.
__global__ __launch_bounds__(64) void build_lists_kernel(
    const int* __restrict__ sb, const int* __restrict__ si,
    int* __restrict__ counts, int* __restrict__ lists){
  int m = blockIdx.x * 64 + threadIdx.x;
  if (m >= M_N) return;
  int a = m % A_N, v = m / A_N;
  int pix = si[a * V_N + v];
  int g = sb[a] * 256 + (pix >> 6);
  int slot = atomicAdd(&counts[g], 1);
  if (slot < LCAP) lists[g * LCAP + slot] = m | ((pix & 63) << 16);
}

// ---------------------------------------------------------------- BN statistics (+ fused gather)
// sums[d] = sum_p h, sums[512+d] = sum_p h^2, h = W1 . x (b1 cancels in BN).
// R7: W1 FRAGMENTS FROM LDS. Six rounds of evidence: all-low counters (MfmaUtil
// 12.8%, VALU 6.9%, HBM 31%) + schedule invariance + MfmaUtil ~= 4 waves x
// (77cy MFMA / ~900cy frag latency) => the per-kk W1 frag loads miss L2 to HBM
// (x stream evicts W1); register double-buffering (R2) cannot hide 900cy.
// Structure: 1 block/CU, grid (256,2), 8 tiles/block. LDS = x tile [64px][512c]
// (64KB) + W1 k-chunk [512d][64c] (64KB). Per tile: stage x (R0 pattern), then
// 8 k-chunks: bulk-stage chunk (8 coalesced bf16x8/thread, grouped) -> barrier ->
// 2 kk-steps with BOTH operands from LDS -> barrier. acc[4][4] persists across
// chunks (full-K h before squaring: exact, same summation order as R0).
// R6 lesson: the ~270-287MB WRITE_SIZE is ambient L3 writeback of the harness's
// input restore (invariant under acc halving; R1's real spill added +320MB on top).
__global__ __launch_bounds__(512, 2) void stats_kernel(
    const float* __restrict__ xS, const float* __restrict__ xT,
    const short* __restrict__ w1S, const short* __restrict__ w1T,
    float* __restrict__ stats,
    const int* __restrict__ counts, const int* __restrict__ lists,
    short* __restrict__ xsS, short* __restrict__ xsT){
  __shared__ short xlds[64 * 512];       // 64 px x 512 c, c XOR-swizzled by ((px&7)<<3)
  __shared__ short wlds[512 * 64];       // 512 d x 64 c chunk, XOR-swizzled by ((d&7)<<3)
  const int t = blockIdx.y;
  const float* __restrict__ x = t ? xT : xS;
  const short* __restrict__ w1 = t ? w1T : w1S;
  float* sums = stats + t * 1024;
  short* __restrict__ xs = t ? xsT : xsS;

  const int tid  = threadIdx.x;
  const int lane = tid & 63;
  const int wave = tid >> 6;
  const int d0   = wave * 64;

  // W1-stage thread mapping (constant across chunks): 8 rows of 64 apart, 128B/row/8lanes
  const int wr = tid >> 3;               // base row 0..63
  const int wc = (tid & 7) * 8;          // col 0..56
  const int wcs = wc ^ ((wr & 7) << 3);  // swizzled col (j*64 doesn't change row&7)

  float rs[4] = {0.f,0.f,0.f,0.f};
  float rq[4] = {0.f,0.f,0.f,0.f};

  for (int it = 0; it < 8; ++it){
    const int g   = blockIdx.x + it * 256;   // n = it (bid < 256), hw0 = bid*64
    const int n   = it;
    const int hw0 = blockIdx.x << 6;
    const float* src = x + ((size_t)(n * CIN + tid)) * HW_SZ + hw0;  // c = tid

    int cnt = counts[g];                 // hoisted: latency hides under staging
    if (cnt > LCAP) cnt = LCAP;

    // stage 64 px x 512 c as bf16 in 4 chunks of 16 px (4 loads in flight/group)
    #pragma unroll
    for (int ch = 0; ch < 4; ++ch){
      float4 v0 = *(const float4*)(src + ch * 16 +  0);
      float4 v1 = *(const float4*)(src + ch * 16 +  4);
      float4 v2 = *(const float4*)(src + ch * 16 +  8);
      float4 v3 = *(const float4*)(src + ch * 16 + 12);
      cvt4(xlds, v0, ch * 16 +  0, tid);
      cvt4(xlds, v1, ch * 16 +  4, tid);
      cvt4(xlds, v2, ch * 16 +  8, tid);
      cvt4(xlds, v3, ch * 16 + 12, tid);
    }
    __syncthreads();

    // fused gather: copy sampled pixel columns (bf16) out of LDS (px packed in list)
    for (int s = 0; s < cnt; ++s){
      int e = lists[g * LCAP + s];
      int m = e & 0xFFFF, px = e >> 16;
      xs[(size_t)m * CIN + tid] = xlds[px * 512 + (tid ^ ((px & 7) << 3))];
    }

    f32x4 acc[4][4] = {};                // [px-tile][d-tile]; accumulates full K
    for (int kc = 0; kc < 8; ++kc){
      // ---- bulk-stage W1 chunk [512 d][kc*64 .. +64): 8 grouped loads/thread
      {
        const short* wsrc = w1 + (size_t)wr * CIN + kc * 64 + wc;
        bf16x8 q0 = *(const bf16x8*)(wsrc + 0 * 64 * CIN);
        bf16x8 q1 = *(const bf16x8*)(wsrc + 1 * 64 * CIN);
        bf16x8 q2 = *(const bf16x8*)(wsrc + 2 * 64 * CIN);
        bf16x8 q3 = *(const bf16x8*)(wsrc + 3 * 64 * CIN);
        bf16x8 q4 = *(const bf16x8*)(wsrc + 4 * 64 * CIN);
        bf16x8 q5 = *(const bf16x8*)(wsrc + 5 * 64 * CIN);
        bf16x8 q6 = *(const bf16x8*)(wsrc + 6 * 64 * CIN);
        bf16x8 q7 = *(const bf16x8*)(wsrc + 7 * 64 * CIN);
        *(bf16x8*)(wlds + (0*64 + wr) * 64 + wcs) = q0;
        *(bf16x8*)(wlds + (1*64 + wr) * 64 + wcs) = q1;
        *(bf16x8*)(wlds + (2*64 + wr) * 64 + wcs) = q2;
        *(bf16x8*)(wlds + (3*64 + wr) * 64 + wcs) = q3;
        *(bf16x8*)(wlds + (4*64 + wr) * 64 + wcs) = q4;
        *(bf16x8*)(wlds + (5*64 + wr) * 64 + wcs) = q5;
        *(bf16x8*)(wlds + (6*64 + wr) * 64 + wcs) = q6;
        *(bf16x8*)(wlds + (7*64 + wr) * 64 + wcs) = q7;
      }
      __syncthreads();                   // chunk ready (prev compute done at loop-end barrier)

      #pragma unroll
      for (int kk2 = 0; kk2 < 2; ++kk2){
        const int kg = kc * 64 + kk2 * 32;           // global k for x tile
        const int kl = kk2 * 32 + ((lane >> 4) << 3);// local k for W1 chunk
        bf16x8 af[4], bf[4];
        #pragma unroll
        for (int pi = 0; pi < 4; ++pi){
          int px = pi * 16 + (lane & 15);
          int c  = (kg + ((lane >> 4) << 3)) ^ ((px & 7) << 3);
          af[pi] = *(const bf16x8*)(xlds + px * 512 + c);
        }
        #pragma unroll
        for (int di = 0; di < 4; ++di){
          int dr = d0 + di * 16 + (lane & 15);
          bf[di] = *(const bf16x8*)(wlds + dr * 64 + (kl ^ ((dr & 7) << 3)));
        }
        #pragma unroll
        for (int pi = 0; pi < 4; ++pi)
          #pragma unroll
          for (int di = 0; di < 4; ++di)
            acc[pi][di] = __builtin_amdgcn_mfma_f32_16x16x32_bf16(af[pi], bf[di], acc[pi][di], 0, 0, 0);
      }
      __syncthreads();                   // compute done before next chunk overwrites wlds
    }

    #pragma unroll
    for (int di = 0; di < 4; ++di){
      float s = 0.f, q2 = 0.f;
      #pragma unroll
      for (int pi = 0; pi < 4; ++pi)
        #pragma unroll
        for (int r = 0; r < 4; ++r){ float vv = acc[pi][di][r]; s += vv; q2 += vv*vv; }
      rs[di] += s; rq[di] += q2;
    }
    // kc-loop's final barrier also fences xlds reads before next tile's staging
  }
  #pragma unroll
  for (int di = 0; di < 4; ++di){
    float s = rs[di], q2 = rq[di];
    s  += __shfl_xor(s, 16, 64);  s  += __shfl_xor(s, 32, 64);
    q2 += __shfl_xor(q2, 16, 64); q2 += __shfl_xor(q2, 32, 64);
    if ((lane & 48) == 0){
      int d = d0 + di*16 + lane;
      atomicAdd(&sums[d], s);
      atomicAdd(&sums[512 + d], q2);
    }
  }
}

// ---------------------------------------------------------------- conv1 + BN + ReLU at samples
__global__ __launch_bounds__(256) void conv1_kernel(
    const short* __restrict__ xsS, const short* __restrict__ xsT,
    const short* __restrict__ w1S, const short* __restrict__ w1T,
    const float* __restrict__ stats,
    const float* __restrict__ gS, const float* __restrict__ bS,
    const float* __restrict__ gT, const float* __restrict__ bT,
    short* __restrict__ hrS, short* __restrict__ hrT){
  const int t = blockIdx.z;
  const short* xs = t ? xsT : xsS;
  const short* w1 = t ? w1T : w1S;
  const float* sums  = stats + t * 1024;
  const float* gamma = t ? gT : gS;
  const float* beta  = t ? bT : bS;
  short* hr = t ? hrT : hrS;

  const int lane = threadIdx.x & 63;
  const int wave = threadIdx.x >> 6;
  const int m0 = blockIdx.x * 16;
  const int d0 = (blockIdx.y * 4 + wave) * 64;

  f32x4 acc[4] = {};
  for (int kk = 0; kk < CIN; kk += 32){
    bf16x8 a = ldfrag(xs, CIN, m0, kk, lane);
    #pragma unroll
    for (int di = 0; di < 4; ++di){
      bf16x8 b = ldfrag(w1, CIN, d0 + di*16, kk, lane);
      acc[di] = __builtin_amdgcn_mfma_f32_16x16x32_bf16(a, b, acc[di], 0, 0, 0);
    }
  }
  const float invP = 1.f / P_TOT;
  #pragma unroll
  for (int di = 0; di < 4; ++di){
    int d = d0 + di*16 + (lane & 15);
    float mu  = sums[d] * invP;
    float var = sums[512 + d] * invP - mu * mu;
    float sc  = gamma[d] * rsqrtf(var + 1e-5f);
    float sh  = beta[d] - mu * sc;
    #pragma unroll
    for (int r = 0; r < 4; ++r){
      int m = m0 + ((lane >> 4) << 2) + r;
      float v = fmaxf(acc[di][r] * sc + sh, 0.f);
      hr[(size_t)m * CIN + d] = f2bf(v);
    }
  }
}

// ---------------------------------------------------------------- conv2 + bias + L2 normalize
__global__ __launch_bounds__(256) void conv2_kernel(
    const short* __restrict__ hrS, const short* __restrict__ hrT,
    const short* __restrict__ w2S, const short* __restrict__ w2T,
    const float* __restrict__ b2S, const float* __restrict__ b2T,
    short* __restrict__ fS, short* __restrict__ fT){
  __shared__ float ssum[4][16];
  const int t = blockIdx.y;
  const short* hr = t ? hrT : hrS;
  const short* w2 = t ? w2T : w2S;
  const float* b2 = t ? b2T : b2S;
  short* f = t ? fT : fS;

  const int lane = threadIdx.x & 63;
  const int wave = threadIdx.x >> 6;
  const int m0 = blockIdx.x * 16;
  const int e0 = wave * 64;

  f32x4 acc[4] = {};
  for (int kk = 0; kk < CIN; kk += 32){
    bf16x8 a = ldfrag(hr, CIN, m0, kk, lane);
    #pragma unroll
    for (int ei = 0; ei < 4; ++ei){
      bf16x8 b = ldfrag(w2, CIN, e0 + ei*16, kk, lane);
      acc[ei] = __builtin_amdgcn_mfma_f32_16x16x32_bf16(a, b, acc[ei], 0, 0, 0);
    }
  }
  float z[4][4];
  float part[4] = {0.f,0.f,0.f,0.f};
  #pragma unroll
  for (int ei = 0; ei < 4; ++ei){
    int e = e0 + ei*16 + (lane & 15);
    float bb = b2[e];
    #pragma unroll
    for (int r = 0; r < 4; ++r){
      float v = acc[ei][r] + bb;
      z[ei][r] = v;
      part[r] += v * v;
    }
  }
  #pragma unroll
  for (int r = 0; r < 4; ++r){
    float p = part[r];
    p += __shfl_xor(p, 1, 64); p += __shfl_xor(p, 2, 64);
    p += __shfl_xor(p, 4, 64); p += __shfl_xor(p, 8, 64);
    part[r] = p;
  }
  if ((lane & 15) == 0){
    #pragma unroll
    for (int r = 0; r < 4; ++r) ssum[wave][((lane >> 4) << 2) + r] = part[r];
  }
  __syncthreads();
  #pragma unroll
  for (int r = 0; r < 4; ++r){
    int mrow = ((lane >> 4) << 2) + r;
    float tot = ssum[0][mrow] + ssum[1][mrow] + ssum[2][mrow] + ssum[3][mrow];
    float sc = 1.f / fmaxf(sqrtf(tot), 1e-12f);
    #pragma unroll
    for (int ei = 0; ei < 4; ++ei){
      int e = e0 + ei*16 + (lane & 15);
      f[(size_t)(m0 + mrow) * FDIM + e] = f2bf(z[ei][r] * sc);
    }
  }
}

// ---------------------------------------------------------------- logits = fa . fb^T / TEMP
// Also writes LT = logits^T when LT != nullptr: logits(fT,fS) == logits(fS,fT)^T
// exactly, so the second logits dispatch is algebraically redundant. Transpose goes
// through a 17-padded LDS tile so LT rows are written as 64B-coalesced chunks.
__global__ __launch_bounds__(64) void logits_kernel(
    const short* __restrict__ fa, const short* __restrict__ fb,
    float* __restrict__ L, float* __restrict__ LT){
  __shared__ float trl[64 * 17];
  const int lane = threadIdx.x;
  const int m0 = blockIdx.x * 16;
  const int n0 = blockIdx.y * 64;
  f32x4 acc[4] = {};
  for (int kk = 0; kk < FDIM; kk += 32){
    bf16x8 a = ldfrag(fa, FDIM, m0, kk, lane);
    #pragma unroll
    for (int ni = 0; ni < 4; ++ni){
      bf16x8 b = ldfrag(fb, FDIM, n0 + ni*16, kk, lane);
      acc[ni] = __builtin_amdgcn_mfma_f32_16x16x32_bf16(a, b, acc[ni], 0, 0, 0);
    }
  }
  #pragma unroll
  for (int ni = 0; ni < 4; ++ni){
    int colL = ni*16 + (lane & 15);
    #pragma unroll
    for (int r = 0; r < 4; ++r){
      int rowL = ((lane >> 4) << 2) + r;
      float val = acc[ni][r] * TEMP_INV;
      L[(size_t)(m0 + rowL) * M_PAD + (n0 + colL)] = val;
      trl[colL * 17 + rowL] = val;
    }
  }
  if (LT){
    __syncthreads();
    float* dst = LT + (size_t)(n0 + lane) * M_PAD + m0;
    #pragma unroll
    for (int jq = 0; jq < 4; ++jq){
      f32x4 tmp;
      tmp.x = trl[lane*17 + jq*4+0];
      tmp.y = trl[lane*17 + jq*4+1];
      tmp.z = trl[lane*17 + jq*4+2];
      tmp.w = trl[lane*17 + jq*4+3];
      *(f32x4*)(dst + jq*4) = tmp;
    }
  }
}

// ---------------------------------------------------------------- per-row contrastive reduction
__global__ __launch_bounds__(256) void loss_kernel(
    const float* __restrict__ L, const int* __restrict__ labels, float* __restrict__ out){
  __shared__ float row[M_N];
  __shared__ float red[4];
  const int m1 = blockIdx.x;
  const int tid = threadIdx.x;
  const int lab1 = labels[m1 % A_N];
  const float* Lr = L + (size_t)m1 * M_PAD;

  float mx = -3.4e38f;
  for (int j = tid; j < M_N; j += 256){ float v = Lr[j]; row[j] = v; mx = fmaxf(mx, v); }
  #pragma unroll
  for (int s = 1; s < 64; s <<= 1) mx = fmaxf(mx, __shfl_xor(mx, s, 64));
  if ((tid & 63) == 0) red[tid >> 6] = mx;
  __syncthreads();
  mx = fmaxf(fmaxf(red[0], red[1]), fmaxf(red[2], red[3]));
  __syncthreads();

  float negp = 0.f;
  for (int j = tid; j < M_N; j += 256){
    int labj = labels[j % A_N];
    float e = __expf(row[j] - mx);
    negp += (labj != lab1) ? e : 0.f;
  }
  #pragma unroll
  for (int s = 1; s < 64; s <<= 1) negp += __shfl_xor(negp, s, 64);
  if ((tid & 63) == 0) red[tid >> 6] = negp;
  __syncthreads();
  float neg = red[0] + red[1] + red[2] + red[3];
  __syncthreads();

  float ps = 0.f, pc = 0.f;
  for (int j = tid; j < M_N; j += 256){
    int labj = labels[j % A_N];
    if (labj == lab1 && j != m1){
      float l = row[j] - mx;
      ps += l - __logf(__expf(l) + neg);
      pc += 1.f;
    }
  }
  #pragma unroll
  for (int s = 1; s < 64; s <<= 1) ps += __shfl_xor(ps, s, 64);
  #pragma unroll
  for (int s = 1; s < 64; s <<= 1) pc += __shfl_xor(pc, s, 64);
  if ((tid & 63) == 0) red[tid >> 6] = ps;
  __syncthreads();
  ps = red[0] + red[1] + red[2] + red[3];
  __syncthreads();
  if ((tid & 63) == 0) red[tid >> 6] = pc;
  __syncthreads();
  if (tid == 0){
    pc = red[0] + red[1] + red[2] + red[3];
    float mlpp = ps / (pc + 1e-6f);
    atomicAdd(out, -0.5f / (float)M_N * mlpp);
  }
}

// ---------------------------------------------------------------- host launch
extern "C" void kernel_launch(void* const* d_in, const int* in_sizes, int n_in,
                              void* d_out, int out_size, void* d_ws, size_t ws_size,
                              hipStream_t stream){
  const float* xS     = (const float*)d_in[0];
  const float* xT     = (const float*)d_in[1];
  const int*   sb     = (const int*)d_in[2];
  const int*   si     = (const int*)d_in[3];
  const int*   labels = (const int*)d_in[4];
  const float* sW1    = (const float*)d_in[5];
  const float* sGamma = (const float*)d_in[7];
  const float* sBeta  = (const float*)d_in[8];
  const float* sW2    = (const float*)d_in[9];
  const float* sB2    = (const float*)d_in[10];
  const float* tW1    = (const float*)d_in[11];
  const float* tGamma = (const float*)d_in[13];
  const float* tBeta  = (const float*)d_in[14];
  const float* tW2    = (const float*)d_in[15];
  const float* tB2    = (const float*)d_in[16];
  float* out = (float*)d_out;

  char* ws = (char*)d_ws;
  size_t off = 0;
  auto alloc = [&](size_t bytes) -> void* {
    void* p = ws + off;
    off = (off + bytes + 255) & ~(size_t)255;
    return p;
  };
  short* w1bS = (short*)alloc((size_t)CIN * CIN * 2);
  short* w1bT = (short*)alloc((size_t)CIN * CIN * 2);
  short* w2bS = (short*)alloc((size_t)FDIM * CIN * 2);
  short* w2bT = (short*)alloc((size_t)FDIM * CIN * 2);
  float* stats = (float*)alloc(2 * 1024 * 4);
  int* counts = (int*)alloc(NGRP * 4);
  int* lists  = (int*)alloc((size_t)NGRP * LCAP * 4);
  short* xsS = (short*)alloc((size_t)M_N * CIN * 2);
  short* xsT = (short*)alloc((size_t)M_N * CIN * 2);
  short* hrS = (short*)alloc((size_t)M_N * CIN * 2);
  short* hrT = (short*)alloc((size_t)M_N * CIN * 2);
  short* fS  = (short*)alloc((size_t)M_PAD * FDIM * 2);
  short* fT  = (short*)alloc((size_t)M_PAD * FDIM * 2);
  float* L   = (float*)alloc((size_t)M_N * M_PAD * 4);
  float* LT  = (float*)alloc((size_t)M_PAD * M_PAD * 4);
  const bool haveLT = (off <= ws_size);   // fall back to two logits passes if tight

  hipMemsetAsync(d_out, 0, sizeof(float), stream);
  hipMemsetAsync(stats, 0, 2 * 1024 * 4, stream);
  hipMemsetAsync(counts, 0, NGRP * 4, stream);
  // zero padded f rows so logits tiles touching them stay finite
  hipMemsetAsync(fS + (size_t)M_N * FDIM, 0, (size_t)(M_PAD - M_N) * FDIM * 2, stream);
  hipMemsetAsync(fT + (size_t)M_N * FDIM, 0, (size_t)(M_PAD - M_N) * FDIM * 2, stream);

  castw_kernel<<<dim3((CIN*CIN + 255) / 256, 4), 256, 0, stream>>>(
      sW1, w1bS, tW1, w1bT, sW2, w2bS, tW2, w2bT);
  build_lists_kernel<<<dim3((M_N + 63) / 64), 64, 0, stream>>>(sb, si, counts, lists);

  stats_kernel<<<dim3(256, 2), 512, 0, stream>>>(xS, xT, w1bS, w1bT, stats,
                                                 counts, lists, xsS, xsT);
  conv1_kernel<<<dim3(247, 2, 2), 256, 0, stream>>>(xsS, xsT, w1bS, w1bT, stats,
                                                    sGamma, sBeta, tGamma, tBeta, hrS, hrT);
  conv2_kernel<<<dim3(247, 2), 256, 0, stream>>>(hrS, hrT, w2bS, w2bT, sB2, tB2, fS, fT);

  if (haveLT){
    logits_kernel<<<dim3(247, 62), 64, 0, stream>>>(fS, fT, L, LT);
    loss_kernel<<<dim3(M_N), 256, 0, stream>>>(L, labels, out);
    loss_kernel<<<dim3(M_N), 256, 0, stream>>>(LT, labels, out);
  } else {
    logits_kernel<<<dim3(247, 62), 64, 0, stream>>>(fS, fT, L, nullptr);
    loss_kernel<<<dim3(M_N), 256, 0, stream>>>(L, labels, out);
    logits_kernel<<<dim3(247, 62), 64, 0, stream>>>(fT, fS, L, nullptr);
    loss_kernel<<<dim3(M_N), 256, 0, stream>>>(L, labels, out);
  }
}